// Round 7
// baseline (126.846 us; speedup 1.0000x reference)
//
#include <hip/hip_runtime.h>

#define B_  16
#define S_  512
#define H_  768
#define T_  9
#define HD_ 64
#define N1  (T_*HD_*2)   // 1152
#define M1  (B_*S_)      // 8192

typedef __attribute__((ext_vector_type(8))) short bf16x8;
typedef __attribute__((ext_vector_type(4))) float f32x4;

#define GLB(p) ((const __attribute__((address_space(1))) void*)(p))
#define LDSP(p) ((__attribute__((address_space(3))) void*)(p))

__device__ inline unsigned short f2bf(float f){
  union { float f; unsigned u; } v; v.f = f;
  unsigned r = v.u + 0x7fffu + ((v.u >> 16) & 1u);   // RNE
  return (unsigned short)(r >> 16);
}

// --- merged prep ---
// blocks [0,3072): hs fp32 -> Abf bf16
// [3072,3936): W [768,1152] -> WtC chunked bf16: (n,k) at ((nb*96 + k/8)*64 + n%64)*8 + k%8
// [3936,4000): trig table [512][32]
__global__ __launch_bounds__(256) void prep_all(
    const float* __restrict__ hs, short* __restrict__ Abf,
    const float* __restrict__ W, short* __restrict__ WtC,
    float2* __restrict__ tab)
{
  __shared__ float tile[32][33];
  const int bx = blockIdx.x, tid = threadIdx.x;
  if(bx < 3072){
    int i = bx*2048 + tid*8;
    float4 a0 = *(const float4*)(hs + i);
    float4 a1 = *(const float4*)(hs + i + 4);
    bf16x8 r;
    r[0]=f2bf(a0.x); r[1]=f2bf(a0.y); r[2]=f2bf(a0.z); r[3]=f2bf(a0.w);
    r[4]=f2bf(a1.x); r[5]=f2bf(a1.y); r[6]=f2bf(a1.z); r[7]=f2bf(a1.w);
    *(bf16x8*)(Abf + i) = r;
  } else if(bx < 3936){
    int idx = bx - 3072;
    int n0 = (idx % 36)*32, k0 = (idx / 36)*32;
    int tx = tid & 31, ty = tid >> 5;
    #pragma unroll
    for(int r = 0; r < 32; r += 8)
      tile[ty + r][tx] = W[(size_t)(k0 + ty + r)*N1 + n0 + tx];
    __syncthreads();
    #pragma unroll
    for(int r = 0; r < 32; r += 8){
      int n = n0 + ty + r, k = k0 + tx;
      size_t off = ((size_t)((n >> 6)*96 + (k >> 3))*64 + (n & 63))*8 + (k & 7);
      WtC[off] = (short)f2bf(tile[tx][ty + r]);
    }
  } else {
    int i = (bx - 3936)*256 + tid;
    int s = i >> 5, p = i & 31;
    float inv = powf(10000.f, -2.f*(float)p/64.f);
    float a = (float)s * inv;
    tab[i] = make_float2(cosf(a), sinf(a));
  }
}

// --- GEMM1: BM=128, BN=64, B LDS-resident per K-half; A direct from global.
// Zero barriers in the K-loop (4 total). 4 waves: 2m x 2n.
__global__ __launch_bounds__(256) void gemm1_rope(
    const short* __restrict__ Abf, const short* __restrict__ WtC,
    const float* __restrict__ bias, const float2* __restrict__ tab,
    short* __restrict__ Qr, short* __restrict__ Kr)
{
  __shared__ short Bs[48*64*8];       // 49152 B: [c(48)][row(64)][8]
  const int tid  = threadIdx.x;
  const int lane = tid & 63, w = tid >> 6;
  const int lr = lane & 15, h = lane >> 4;    // h in 0..3
  const int wm = (w >> 1) * 64, wn = (w & 1) * 32;
  const int nb = blockIdx.x;          // n-block (fastest: consecutive blocks share A-tile)
  const int n0 = nb * 64;
  const int m0 = blockIdx.y * 128;

  f32x4 acc[4][2] = {};

  const short* aBase = Abf + (size_t)(m0 + wm + lr) * H_ + h*8;
  const size_t wsrc = (size_t)nb * 96 * 64 * 8;   // this n-block's chunk region

  for(int h2 = 0; h2 < 2; ++h2){
    if(h2) __builtin_amdgcn_s_barrier();          // all waves done reading half-0
    #pragma unroll
    for(int q = 0; q < 12; ++q){
      // chunk c = h2*48 + q*4 + w, row = lane  -> LDS linear slot (q*256+tid)*16B
      __builtin_amdgcn_global_load_lds(
        GLB(WtC + wsrc + ((size_t)((h2*48 + q*4 + w)*64 + lane))*8),
        LDSP(Bs + (q*256 + tid)*8), 16, 0, 0);
    }
    asm volatile("s_waitcnt vmcnt(0)" ::: "memory");
    __builtin_amdgcn_s_barrier();

    #pragma unroll
    for(int ks = 0; ks < 12; ++ks){
      bf16x8 aF[4], bF[2];
      #pragma unroll
      for(int i = 0; i < 4; ++i)
        aF[i] = *(const bf16x8*)(aBase + (size_t)i*16*H_ + h2*384 + ks*32);
      #pragma unroll
      for(int j = 0; j < 2; ++j)
        bF[j] = *(const bf16x8*)(Bs + ((ks*4 + h)*64 + (wn + j*16 + lr))*8);
      #pragma unroll
      for(int i = 0; i < 4; ++i)
        #pragma unroll
        for(int j = 0; j < 2; ++j)
          acc[i][j] = __builtin_amdgcn_mfma_f32_16x16x32_bf16(bF[j], aF[i], acc[i][j], 0, 0, 0);
    }
  }

  // epilogue: bias + lane-local RoPE + packed 4B stores (regs = 4 consecutive n)
  const int t = n0 >> 7;
  #pragma unroll
  for(int i = 0; i < 4; ++i){
    int m  = m0 + wm + i*16 + lr;
    int bi = m >> 9, sp = m & 511;
    size_t rowoff = ((size_t)(bi*T_ + t)*S_ + sp)*HD_;
    #pragma unroll
    for(int j = 0; j < 2; ++j){
      int nq  = n0 + wn + j*16 + (h << 2);
      int hd0 = (nq >> 1) & 63;
      int p   = (nq >> 2) & 31;
      float4 bv = *(const float4*)(bias + nq);
      float2 cs = tab[sp*32 + p];
      float q0 = acc[i][j][0] + bv.x;
      float k0v= acc[i][j][1] + bv.y;
      float q1 = acc[i][j][2] + bv.z;
      float k1v= acc[i][j][3] + bv.w;
      float rq0 = q0*cs.x - q1*cs.y, rq1 = q1*cs.x + q0*cs.y;
      float rk0 = k0v*cs.x - k1v*cs.y, rk1 = k1v*cs.x + k0v*cs.y;
      unsigned uq = (unsigned)f2bf(rq0) | ((unsigned)f2bf(rq1) << 16);
      unsigned uk = (unsigned)f2bf(rk0) | ((unsigned)f2bf(rk1) << 16);
      *(unsigned*)(Qr + rowoff + hd0) = uq;
      *(unsigned*)(Kr + rowoff + hd0) = uk;
    }
  }
}

// --- biaffine (swapped operands): lane holds 4 consecutive n -> float4 store ---
__global__ __launch_bounds__(256) void gemm2_mask(
    const short* __restrict__ Qr, const short* __restrict__ Kr,
    const int* __restrict__ am, float* __restrict__ out)
{
  const int lane = threadIdx.x & 63;
  const int w    = threadIdx.x >> 6;
  const int bt   = blockIdx.z;
  const int b    = bt / T_;
  const int n0   = blockIdx.x * 128 + (w & 1) * 64;
  const int m0   = blockIdx.y * 128 + (w >> 1) * 64;
  const int lr   = lane & 15;
  const int lk   = (lane >> 4) * 8;

  const short* Q = Qr + (size_t)bt * S_ * HD_;
  const short* K = Kr + (size_t)bt * S_ * HD_;
  f32x4 acc[4][4] = {};

  #pragma unroll
  for(int ks = 0; ks < HD_; ks += 32){
    bf16x8 aF[4], bF[4];
    #pragma unroll
    for(int i = 0; i < 4; ++i) aF[i] = *(const bf16x8*)(Q + (size_t)(m0 + i*16 + lr)*HD_ + ks + lk);
    #pragma unroll
    for(int j = 0; j < 4; ++j) bF[j] = *(const bf16x8*)(K + (size_t)(n0 + j*16 + lr)*HD_ + ks + lk);
    #pragma unroll
    for(int i = 0; i < 4; ++i)
      #pragma unroll
      for(int j = 0; j < 4; ++j)
        acc[i][j] = __builtin_amdgcn_mfma_f32_16x16x32_bf16(bF[j], aF[i], acc[i][j], 0, 0, 0);
  }

  const int* amb = am + b * S_;
  #pragma unroll
  for(int i = 0; i < 4; ++i){
    int m = m0 + i*16 + lr;
    float amm = (float)amb[m];
    float* orow = out + ((size_t)bt*S_ + m)*S_;
    #pragma unroll
    for(int j = 0; j < 4; ++j){
      int nq = n0 + j*16 + ((lane >> 4) << 2);
      int4 a4 = *(const int4*)(amb + nq);
      float4 r;
      r.x = acc[i][j][0]*0.125f - (1.f - amm*(float)a4.x)*1e12f - ((nq+0) < m ? 1e12f : 0.f);
      r.y = acc[i][j][1]*0.125f - (1.f - amm*(float)a4.y)*1e12f - ((nq+1) < m ? 1e12f : 0.f);
      r.z = acc[i][j][2]*0.125f - (1.f - amm*(float)a4.z)*1e12f - ((nq+2) < m ? 1e12f : 0.f);
      r.w = acc[i][j][3]*0.125f - (1.f - amm*(float)a4.w)*1e12f - ((nq+3) < m ? 1e12f : 0.f);
      *(float4*)(orow + nq) = r;
    }
  }
}

extern "C" void kernel_launch(void* const* d_in, const int* in_sizes, int n_in,
                              void* d_out, int out_size, void* d_ws, size_t ws_size,
                              hipStream_t stream)
{
  const float* hs    = (const float*)d_in[0];
  const int*   amask = (const int*)  d_in[1];
  const float* W     = (const float*)d_in[2];
  const float* bias  = (const float*)d_in[3];
  float* out = (float*)d_out;

  char* ws = (char*)d_ws;
  short*  WtC = (short*) (ws);                       // 1,769,472 B (chunked layout)
  float2* tab = (float2*)(ws + 1769472);             //   131,072 B
  short*  Qr  = (short*) (ws + 1900544);             // 9,437,184 B
  short*  Kr  = (short*) (ws + 11337728);            // 9,437,184 B
  short*  Abf = (short*) (ws + 20774912);            // 12,582,912 B

  prep_all  <<<4000, 256, 0, stream>>>(hs, Abf, W, WtC, tab);
  gemm1_rope<<<dim3(N1/64, M1/128), 256, 0, stream>>>(Abf, WtC, bias, tab, Qr, Kr);
  gemm2_mask<<<dim3(S_/128, S_/128, B_*T_), 256, 0, stream>>>(Qr, Kr, amask, out);
}

// Round 8
// 107.523 us; speedup vs baseline: 1.1797x; 1.1797x over previous
//
#include <hip/hip_runtime.h>

#define B_  16
#define S_  512
#define H_  768
#define T_  9
#define HD_ 64
#define N1  (T_*HD_*2)   // 1152
#define M1  (B_*S_)      // 8192

typedef __attribute__((ext_vector_type(8))) short bf16x8;
typedef __attribute__((ext_vector_type(4))) float f32x4;

__device__ inline unsigned short f2bf(float f){
  union { float f; unsigned u; } v; v.f = f;
  unsigned r = v.u + 0x7fffu + ((v.u >> 16) & 1u);   // RNE
  return (unsigned short)(r >> 16);
}

// Chunk layout: elem (row, k) of a 128-row tile lives at
//   ((tile*96 + k/8)*128 + row%128)*8 + k%8        (96 = 768/8 k-chunks)
// => a wave's 16-lane x bf16x8 fragment load (rows consecutive, k-chunk per
//    h-group) is 4 contiguous 256B segments = dense 1KB. Fully coalesced.

// --- merged prep ---
// [0,768):      hs fp32 -> AbfC chunked bf16  (64 mtiles x 12 kb-blocks)
// [768,1632):   W [768,1152] -> WtC chunked bf16 (transpose, 36x24 32x32 tiles)
// [1632,1696):  trig table [512][32]
__global__ __launch_bounds__(256) void prep_all(
    const float* __restrict__ hs, short* __restrict__ AbfC,
    const float* __restrict__ W, short* __restrict__ WtC,
    float2* __restrict__ tab)
{
  __shared__ float tile[32][33];
  const int bx = blockIdx.x, tid = threadIdx.x;
  if(bx < 768){
    int mb = bx / 12, kb = bx % 12;
    int kc = kb*8 + (tid >> 5);          // global k-chunk 0..95
    int m4 = (tid & 31) * 4;
    const float* src = hs + (size_t)mb*128*768 + kc*8;
    short* dst = AbfC + ((size_t)mb*96 + kc)*128*8;
    #pragma unroll
    for(int q = 0; q < 4; ++q){
      int m = m4 + q;
      float4 a0 = *(const float4*)(src + (size_t)m*768);
      float4 a1 = *(const float4*)(src + (size_t)m*768 + 4);
      bf16x8 r;
      r[0]=f2bf(a0.x); r[1]=f2bf(a0.y); r[2]=f2bf(a0.z); r[3]=f2bf(a0.w);
      r[4]=f2bf(a1.x); r[5]=f2bf(a1.y); r[6]=f2bf(a1.z); r[7]=f2bf(a1.w);
      *(bf16x8*)(dst + (size_t)m*8) = r;
    }
  } else if(bx < 1632){
    int idx = bx - 768;
    int n0 = (idx % 36)*32, k0 = (idx / 36)*32;
    int tx = tid & 31, ty = tid >> 5;
    #pragma unroll
    for(int r = 0; r < 32; r += 8)
      tile[ty + r][tx] = W[(size_t)(k0 + ty + r)*N1 + n0 + tx];
    __syncthreads();
    #pragma unroll
    for(int r = 0; r < 32; r += 8){
      int n = n0 + ty + r, k = k0 + tx;
      size_t off = (((size_t)(n >> 7)*96 + (k >> 3))*128 + (n & 127))*8 + (k & 7);
      WtC[off] = (short)f2bf(tile[tx][ty + r]);
    }
  } else {
    int i = (bx - 1632)*256 + tid;
    int s = i >> 5, p = i & 31;
    float inv = powf(10000.f, -2.f*(float)p/64.f);
    float a = (float)s * inv;
    tab[i] = make_float2(cosf(a), sinf(a));
  }
}

// --- GEMM1: zero-LDS, zero-barrier register GEMM on chunked operands.
// 128x128 tile, 4 waves (2m x 2n), 64x64 per wave. Swapped-operand MFMA:
// lane regs hold 4 consecutive n = {q(hd0),k(hd0),q(hd0+1),k(hd0+1)}.
__global__ __launch_bounds__(256) void gemm1_rope(
    const short* __restrict__ AbfC, const short* __restrict__ WtC,
    const float* __restrict__ bias, const float2* __restrict__ tab,
    short* __restrict__ Qr, short* __restrict__ Kr)
{
  const int tid  = threadIdx.x;
  const int lane = tid & 63, w = tid >> 6;
  const int lr = lane & 15, h = lane >> 4;
  const int wm = (w >> 1) * 64, wn = (w & 1) * 64;
  const int nb = blockIdx.x, mb = blockIdx.y;
  const int n0 = nb * 128, m0 = mb * 128;

  const short* aB = AbfC + (((size_t)mb*96 + h)*128 + (wm + lr))*8;
  const short* bB = WtC  + (((size_t)nb*96 + h)*128 + (wn + lr))*8;

  f32x4 acc[4][4] = {};

  for(int ks = 0; ks < 24; ++ks){
    bf16x8 aF[4], bF[4];
    const size_t ko = (size_t)ks*4*128*8;
    #pragma unroll
    for(int i = 0; i < 4; ++i) aF[i] = *(const bf16x8*)(aB + ko + (size_t)i*16*8);
    #pragma unroll
    for(int j = 0; j < 4; ++j) bF[j] = *(const bf16x8*)(bB + ko + (size_t)j*16*8);
    #pragma unroll
    for(int i = 0; i < 4; ++i)
      #pragma unroll
      for(int j = 0; j < 4; ++j)
        acc[i][j] = __builtin_amdgcn_mfma_f32_16x16x32_bf16(bF[j], aF[i], acc[i][j], 0, 0, 0);
  }

  // epilogue: bias + lane-local RoPE + packed 4B stores
  const int t = nb;                     // n-tile of 128 == one entity type
  #pragma unroll
  for(int i = 0; i < 4; ++i){
    int m  = m0 + wm + i*16 + lr;
    int bi = m >> 9, sp = m & 511;
    size_t rowoff = ((size_t)(bi*T_ + t)*S_ + sp)*HD_;
    #pragma unroll
    for(int j = 0; j < 4; ++j){
      int nq  = n0 + wn + j*16 + (h << 2);
      int hd0 = (nq >> 1) & 63;
      int p   = (nq >> 2) & 31;
      float4 bv = *(const float4*)(bias + nq);
      float2 cs = tab[sp*32 + p];
      float q0 = acc[i][j][0] + bv.x;
      float k0v= acc[i][j][1] + bv.y;
      float q1 = acc[i][j][2] + bv.z;
      float k1v= acc[i][j][3] + bv.w;
      float rq0 = q0*cs.x - q1*cs.y, rq1 = q1*cs.x + q0*cs.y;
      float rk0 = k0v*cs.x - k1v*cs.y, rk1 = k1v*cs.x + k0v*cs.y;
      unsigned uq = (unsigned)f2bf(rq0) | ((unsigned)f2bf(rq1) << 16);
      unsigned uk = (unsigned)f2bf(rk0) | ((unsigned)f2bf(rk1) << 16);
      *(unsigned*)(Qr + rowoff + hd0) = uq;
      *(unsigned*)(Kr + rowoff + hd0) = uk;
    }
  }
}

// --- biaffine (swapped operands): lane holds 4 consecutive n -> float4 store ---
__global__ __launch_bounds__(256) void gemm2_mask(
    const short* __restrict__ Qr, const short* __restrict__ Kr,
    const int* __restrict__ am, float* __restrict__ out)
{
  const int lane = threadIdx.x & 63;
  const int w    = threadIdx.x >> 6;
  const int bt   = blockIdx.z;
  const int b    = bt / T_;
  const int n0   = blockIdx.x * 128 + (w & 1) * 64;
  const int m0   = blockIdx.y * 128 + (w >> 1) * 64;
  const int lr   = lane & 15;
  const int lk   = (lane >> 4) * 8;

  const short* Q = Qr + (size_t)bt * S_ * HD_;
  const short* K = Kr + (size_t)bt * S_ * HD_;
  f32x4 acc[4][4] = {};

  #pragma unroll
  for(int ks = 0; ks < HD_; ks += 32){
    bf16x8 aF[4], bF[4];
    #pragma unroll
    for(int i = 0; i < 4; ++i) aF[i] = *(const bf16x8*)(Q + (size_t)(m0 + i*16 + lr)*HD_ + ks + lk);
    #pragma unroll
    for(int j = 0; j < 4; ++j) bF[j] = *(const bf16x8*)(K + (size_t)(n0 + j*16 + lr)*HD_ + ks + lk);
    #pragma unroll
    for(int i = 0; i < 4; ++i)
      #pragma unroll
      for(int j = 0; j < 4; ++j)
        acc[i][j] = __builtin_amdgcn_mfma_f32_16x16x32_bf16(bF[j], aF[i], acc[i][j], 0, 0, 0);
  }

  const int* amb = am + b * S_;
  #pragma unroll
  for(int i = 0; i < 4; ++i){
    int m = m0 + i*16 + lr;
    float amm = (float)amb[m];
    float* orow = out + ((size_t)bt*S_ + m)*S_;
    #pragma unroll
    for(int j = 0; j < 4; ++j){
      int nq = n0 + j*16 + ((lane >> 4) << 2);
      int4 a4 = *(const int4*)(amb + nq);
      float4 r;
      r.x = acc[i][j][0]*0.125f - (1.f - amm*(float)a4.x)*1e12f - ((nq+0) < m ? 1e12f : 0.f);
      r.y = acc[i][j][1]*0.125f - (1.f - amm*(float)a4.y)*1e12f - ((nq+1) < m ? 1e12f : 0.f);
      r.z = acc[i][j][2]*0.125f - (1.f - amm*(float)a4.z)*1e12f - ((nq+2) < m ? 1e12f : 0.f);
      r.w = acc[i][j][3]*0.125f - (1.f - amm*(float)a4.w)*1e12f - ((nq+3) < m ? 1e12f : 0.f);
      *(float4*)(orow + nq) = r;
    }
  }
}

extern "C" void kernel_launch(void* const* d_in, const int* in_sizes, int n_in,
                              void* d_out, int out_size, void* d_ws, size_t ws_size,
                              hipStream_t stream)
{
  const float* hs    = (const float*)d_in[0];
  const int*   amask = (const int*)  d_in[1];
  const float* W     = (const float*)d_in[2];
  const float* bias  = (const float*)d_in[3];
  float* out = (float*)d_out;

  char* ws = (char*)d_ws;
  short*  WtC  = (short*) (ws);                      // 1,769,472 B (chunked)
  float2* tab  = (float2*)(ws + 1769472);            //   131,072 B
  short*  Qr   = (short*) (ws + 1900544);            // 9,437,184 B
  short*  Kr   = (short*) (ws + 11337728);           // 9,437,184 B
  short*  AbfC = (short*) (ws + 20774912);           // 12,582,912 B (chunked)

  prep_all  <<<1696, 256, 0, stream>>>(hs, AbfC, W, WtC, tab);
  gemm1_rope<<<dim3(N1/128, M1/128), 256, 0, stream>>>(AbfC, WtC, bias, tab, Qr, Kr);
  gemm2_mask<<<dim3(S_/128, S_/128, B_*T_), 256, 0, stream>>>(Qr, Kr, amask, out);
}